// Round 1
// baseline (437.309 us; speedup 1.0000x reference)
//
#include <hip/hip_runtime.h>
#include <math.h>

#define T 2048
#define HD 1024
#define ID 2048
#define NE 8

typedef short bf16x8 __attribute__((ext_vector_type(8)));
typedef float f32x4 __attribute__((ext_vector_type(4)));
typedef unsigned short u16x8 __attribute__((ext_vector_type(8)));

__device__ __forceinline__ unsigned short f2bf(float f) {
  union { float f; unsigned u; } v; v.f = f;
  unsigned r = v.u + 0x7FFFu + ((v.u >> 16) & 1u);
  return (unsigned short)(r >> 16);
}

__device__ __forceinline__ u16x8 cvt8(float4 a, float4 b) {
  u16x8 o;
  o[0] = f2bf(a.x); o[1] = f2bf(a.y); o[2] = f2bf(a.z); o[3] = f2bf(a.w);
  o[4] = f2bf(b.x); o[5] = f2bf(b.y); o[6] = f2bf(b.z); o[7] = f2bf(b.w);
  return o;
}

// ---------- cast x (fp32) -> xb (bf16) ----------
__global__ __launch_bounds__(256) void cast_x_kernel(
    const float* __restrict__ x, unsigned short* __restrict__ xb) {
  int idx = (blockIdx.x * 256 + threadIdx.x) * 8;
  float4 f0 = *(const float4*)(x + idx);
  float4 f1 = *(const float4*)(x + idx + 4);
  *(u16x8*)(xb + idx) = cvt8(f0, f1);
}

// ---------- router: logits (fp32, exact), top-2, gates, per-expert lists ----
__global__ __launch_bounds__(256) void router_kernel(
    const float* __restrict__ x, const float* __restrict__ rw,
    float* __restrict__ logits_out, int* __restrict__ pair_rowid,
    float* __restrict__ pair_gate, int* __restrict__ counts) {
  __shared__ float rws[NE * HD];
  int tid = threadIdx.x;
  for (int j = tid * 4; j < NE * HD; j += 256 * 4)
    *(float4*)&rws[j] = *(const float4*)&rw[j];
  __syncthreads();
  int wid = tid >> 6, lane = tid & 63;
  int t = blockIdx.x * 4 + wid;
  float acc[NE];
#pragma unroll
  for (int e = 0; e < NE; e++) acc[e] = 0.f;
  const float* xrow = x + (size_t)t * HD;
  for (int j = 0; j < HD; j += 64) {
    float xv = xrow[j + lane];
#pragma unroll
    for (int e = 0; e < NE; e++) acc[e] += xv * rws[e * HD + j + lane];
  }
#pragma unroll
  for (int e = 0; e < NE; e++)
    for (int off = 32; off > 0; off >>= 1) acc[e] += __shfl_xor(acc[e], off, 64);
  if (lane == 0) {
#pragma unroll
    for (int e = 0; e < NE; e++) logits_out[t * NE + e] = acc[e];
    int e0 = 0;
#pragma unroll
    for (int e = 1; e < NE; e++) if (acc[e] > acc[e0]) e0 = e;
    int e1 = (e0 == 0) ? 1 : 0;
#pragma unroll
    for (int e = 0; e < NE; e++)
      if (e != e0 && e != e1 && acc[e] > acc[e1]) e1 = e;
    // renormalized top-2 softmax == softmax over {l0,l1}
    float b = __expf(acc[e1] - acc[e0]);
    float g0 = 1.f / (1.f + b);
    float g1 = 1.f - g0;
    int p0 = atomicAdd(&counts[e0], 1);
    pair_rowid[e0 * T + p0] = t * 2;
    pair_gate[e0 * T + p0] = g0;
    int p1 = atomicAdd(&counts[e1], 1);
    pair_rowid[e1 * T + p1] = t * 2 + 1;
    pair_gate[e1 * T + p1] = g1;
  }
}

// ---------- GEMM1: h = gelu(x@w1_e^T) * (x@v_e^T), gathered rows -> hb bf16 -
__global__ __launch_bounds__(256) void gemm1_kernel(
    const unsigned short* __restrict__ xb, const float* __restrict__ w1,
    const float* __restrict__ v, unsigned short* __restrict__ hb,
    const int* __restrict__ pair_rowid, const int* __restrict__ counts) {
  int e = blockIdx.z;
  int cnt = counts[e];
  int row0 = blockIdx.y * 64;
  if (row0 >= cnt) return;
  __shared__ unsigned short As[64][40];
  __shared__ unsigned short B1s[64][40];
  __shared__ unsigned short B2s[64][40];
  __shared__ int rids[64];
  int tid = threadIdx.x;
  if (tid < 64) {
    int idx = row0 + tid;
    if (idx > cnt - 1) idx = cnt - 1;
    rids[tid] = pair_rowid[e * T + idx];
  }
  __syncthreads();
  int lane = tid & 63, wid = tid >> 6;
  int wr = wid >> 1, wc = wid & 1;
  int r_st = tid >> 2, ks = (tid & 3) * 8;
  int col0 = blockIdx.x * 64;
  f32x4 acc1[2][2] = {};
  f32x4 acc3[2][2] = {};
  const float* w1base = w1 + ((size_t)e * ID + col0 + r_st) * HD + ks;
  const float* vbase  = v  + ((size_t)e * ID + col0 + r_st) * HD + ks;
  int tok = rids[r_st] >> 1;
  const unsigned short* abase = xb + (size_t)tok * HD + ks;
  int mrow = lane & 15, kq = (lane >> 4) * 8;
  for (int kt = 0; kt < HD; kt += 32) {
    *(uint4*)&As[r_st][ks] = *(const uint4*)(abase + kt);
    {
      float4 f0 = *(const float4*)(w1base + kt);
      float4 f1 = *(const float4*)(w1base + kt + 4);
      *(u16x8*)&B1s[r_st][ks] = cvt8(f0, f1);
    }
    {
      float4 f0 = *(const float4*)(vbase + kt);
      float4 f1 = *(const float4*)(vbase + kt + 4);
      *(u16x8*)&B2s[r_st][ks] = cvt8(f0, f1);
    }
    __syncthreads();
    bf16x8 a[2], b1[2], b2[2];
    a[0]  = *(const bf16x8*)&As[wr * 32 + mrow][kq];
    a[1]  = *(const bf16x8*)&As[wr * 32 + 16 + mrow][kq];
    b1[0] = *(const bf16x8*)&B1s[wc * 32 + mrow][kq];
    b1[1] = *(const bf16x8*)&B1s[wc * 32 + 16 + mrow][kq];
    b2[0] = *(const bf16x8*)&B2s[wc * 32 + mrow][kq];
    b2[1] = *(const bf16x8*)&B2s[wc * 32 + 16 + mrow][kq];
#pragma unroll
    for (int mi = 0; mi < 2; mi++)
#pragma unroll
      for (int ni = 0; ni < 2; ni++) {
        acc1[mi][ni] = __builtin_amdgcn_mfma_f32_16x16x32_bf16(a[mi], b1[ni], acc1[mi][ni], 0, 0, 0);
        acc3[mi][ni] = __builtin_amdgcn_mfma_f32_16x16x32_bf16(a[mi], b2[ni], acc3[mi][ni], 0, 0, 0);
      }
    __syncthreads();
  }
  int dcol = lane & 15, drow4 = (lane >> 4) * 4;
#pragma unroll
  for (int mi = 0; mi < 2; mi++)
#pragma unroll
    for (int ni = 0; ni < 2; ni++)
#pragma unroll
      for (int r = 0; r < 4; r++) {
        int lr = wr * 32 + mi * 16 + drow4 + r;
        if (row0 + lr < cnt) {
          float g1v = acc1[mi][ni][r];
          float g3v = acc3[mi][ni][r];
          // exact gelu: x * 0.5 * (1 + erf(x/sqrt(2)))
          float hval = 0.5f * g1v * (1.f + erff(g1v * 0.70710678118654752f)) * g3v;
          int rowid = rids[lr];
          hb[(size_t)rowid * ID + col0 + wc * 32 + ni * 16 + dcol] = f2bf(hval);
        }
      }
}

// ---------- GEMM2: y = h @ w2_e^T, gate, atomic-add into out ----------
__global__ __launch_bounds__(256) void gemm2_kernel(
    const unsigned short* __restrict__ hb, const float* __restrict__ w2,
    float* __restrict__ out, const int* __restrict__ pair_rowid,
    const float* __restrict__ pair_gate, const int* __restrict__ counts) {
  int e = blockIdx.z;
  int cnt = counts[e];
  int row0 = blockIdx.y * 64;
  if (row0 >= cnt) return;
  __shared__ unsigned short As[64][40];
  __shared__ unsigned short Bs[64][40];
  __shared__ int rids[64];
  __shared__ float gts[64];
  int tid = threadIdx.x;
  if (tid < 64) {
    int idx = row0 + tid;
    if (idx > cnt - 1) idx = cnt - 1;
    rids[tid] = pair_rowid[e * T + idx];
    gts[tid] = pair_gate[e * T + idx];
  }
  __syncthreads();
  int lane = tid & 63, wid = tid >> 6;
  int wr = wid >> 1, wc = wid & 1;
  int r_st = tid >> 2, ks = (tid & 3) * 8;
  int col0 = blockIdx.x * 64;
  f32x4 acc[2][2] = {};
  const float* w2base = w2 + ((size_t)e * HD + col0 + r_st) * ID + ks;
  const unsigned short* abase = hb + (size_t)rids[r_st] * ID + ks;
  int mrow = lane & 15, kq = (lane >> 4) * 8;
  for (int kt = 0; kt < ID; kt += 32) {
    *(uint4*)&As[r_st][ks] = *(const uint4*)(abase + kt);
    {
      float4 f0 = *(const float4*)(w2base + kt);
      float4 f1 = *(const float4*)(w2base + kt + 4);
      *(u16x8*)&Bs[r_st][ks] = cvt8(f0, f1);
    }
    __syncthreads();
    bf16x8 a[2], b[2];
    a[0] = *(const bf16x8*)&As[wr * 32 + mrow][kq];
    a[1] = *(const bf16x8*)&As[wr * 32 + 16 + mrow][kq];
    b[0] = *(const bf16x8*)&Bs[wc * 32 + mrow][kq];
    b[1] = *(const bf16x8*)&Bs[wc * 32 + 16 + mrow][kq];
#pragma unroll
    for (int mi = 0; mi < 2; mi++)
#pragma unroll
      for (int ni = 0; ni < 2; ni++)
        acc[mi][ni] = __builtin_amdgcn_mfma_f32_16x16x32_bf16(a[mi], b[ni], acc[mi][ni], 0, 0, 0);
    __syncthreads();
  }
  int dcol = lane & 15, drow4 = (lane >> 4) * 4;
#pragma unroll
  for (int mi = 0; mi < 2; mi++)
#pragma unroll
    for (int ni = 0; ni < 2; ni++)
#pragma unroll
      for (int r = 0; r < 4; r++) {
        int lr = wr * 32 + mi * 16 + drow4 + r;
        if (row0 + lr < cnt) {
          int tokrow = rids[lr] >> 1;
          float val = gts[lr] * acc[mi][ni][r];
          atomicAdd(&out[(size_t)tokrow * HD + col0 + wc * 32 + ni * 16 + dcol], val);
        }
      }
}

extern "C" void kernel_launch(void* const* d_in, const int* in_sizes, int n_in,
                              void* d_out, int out_size, void* d_ws, size_t ws_size,
                              hipStream_t stream) {
  const float* x  = (const float*)d_in[0];
  const float* rw = (const float*)d_in[1];
  const float* w1 = (const float*)d_in[2];
  const float* v  = (const float*)d_in[3];
  const float* w2 = (const float*)d_in[4];
  float* out = (float*)d_out;
  float* logits_out = out + (size_t)T * HD;

  char* ws = (char*)d_ws;
  unsigned short* xb = (unsigned short*)(ws);                       // 4 MB
  unsigned short* hb = (unsigned short*)(ws + 4194304);             // 16 MB
  int*   pair_rowid  = (int*)  (ws + 20971520);                     // 64 KB
  float* pair_gate   = (float*)(ws + 21037056);                     // 64 KB
  int*   counts      = (int*)  (ws + 21102592);                     // 32 B

  // zero accumulator output region + expert counts (ws is poisoned 0xAA)
  hipMemsetAsync(out, 0, (size_t)T * HD * sizeof(float), stream);
  hipMemsetAsync(counts, 0, NE * sizeof(int), stream);

  cast_x_kernel<<<(T * HD) / (256 * 8), 256, 0, stream>>>(x, xb);
  router_kernel<<<T / 4, 256, 0, stream>>>(x, rw, logits_out, pair_rowid,
                                           pair_gate, counts);
  // GEMM1: grid (colTiles=I/64, worst-case rowTiles=T/64, experts)
  gemm1_kernel<<<dim3(ID / 64, T / 64, NE), 256, 0, stream>>>(
      xb, w1, v, hb, pair_rowid, counts);
  // GEMM2: grid (colTiles=H/64, worst-case rowTiles=T/64, experts)
  gemm2_kernel<<<dim3(HD / 64, T / 64, NE), 256, 0, stream>>>(
      hb, w2, out, pair_rowid, pair_gate, counts);
}

// Round 2
// 426.698 us; speedup vs baseline: 1.0249x; 1.0249x over previous
//
#include <hip/hip_runtime.h>
#include <math.h>

#define T 2048
#define HD 1024
#define ID 2048
#define NE 8

typedef short bf16x8 __attribute__((ext_vector_type(8)));
typedef float f32x4 __attribute__((ext_vector_type(4)));
typedef unsigned short u16x8 __attribute__((ext_vector_type(8)));

__device__ __forceinline__ unsigned short f2bf(float f) {
  union { float f; unsigned u; } v; v.f = f;
  unsigned r = v.u + 0x7FFFu + ((v.u >> 16) & 1u);
  return (unsigned short)(r >> 16);
}

__device__ __forceinline__ u16x8 cvt8(float4 a, float4 b) {
  u16x8 o;
  o[0] = f2bf(a.x); o[1] = f2bf(a.y); o[2] = f2bf(a.z); o[3] = f2bf(a.w);
  o[4] = f2bf(b.x); o[5] = f2bf(b.y); o[6] = f2bf(b.z); o[7] = f2bf(b.w);
  return o;
}

// async global->LDS, 16B per lane; LDS dest = wave-uniform base + lane*16
__device__ __forceinline__ void glds16(const unsigned short* g, unsigned short* l) {
  __builtin_amdgcn_global_load_lds(
      (const __attribute__((address_space(1))) unsigned int*)(g),
      (__attribute__((address_space(3))) unsigned int*)(l), 16, 0, 0);
}

// ---------- cast x (fp32) -> xb (bf16) ----------
__global__ __launch_bounds__(256) void cast_x_kernel(
    const float* __restrict__ x, unsigned short* __restrict__ xb) {
  size_t idx = ((size_t)blockIdx.x * 256 + threadIdx.x) * 8;
  float4 f0 = *(const float4*)(x + idx);
  float4 f1 = *(const float4*)(x + idx + 4);
  *(u16x8*)(xb + idx) = cvt8(f0, f1);
}

// ---------- cast weights (fp32) -> bf16, 3 tensors via blockIdx.y ----------
__global__ __launch_bounds__(256) void cast_w_kernel(
    const float* __restrict__ s0, const float* __restrict__ s1,
    const float* __restrict__ s2, unsigned short* __restrict__ d0,
    unsigned short* __restrict__ d1, unsigned short* __restrict__ d2) {
  const float* s; unsigned short* d;
  if (blockIdx.y == 0)      { s = s0; d = d0; }
  else if (blockIdx.y == 1) { s = s1; d = d1; }
  else                      { s = s2; d = d2; }
  size_t idx = ((size_t)blockIdx.x * 256 + threadIdx.x) * 8;
  float4 f0 = *(const float4*)(s + idx);
  float4 f1 = *(const float4*)(s + idx + 4);
  *(u16x8*)(d + idx) = cvt8(f0, f1);
}

// ---------- router: logits (fp32, exact), top-2, gates, per-expert lists ----
__global__ __launch_bounds__(256) void router_kernel(
    const float* __restrict__ x, const float* __restrict__ rw,
    float* __restrict__ logits_out, int* __restrict__ pair_rowid,
    float* __restrict__ pair_gate, int* __restrict__ counts) {
  __shared__ float rws[NE * HD];
  int tid = threadIdx.x;
  for (int j = tid * 4; j < NE * HD; j += 256 * 4)
    *(float4*)&rws[j] = *(const float4*)&rw[j];
  __syncthreads();
  int wid = tid >> 6, lane = tid & 63;
  int t = blockIdx.x * 4 + wid;
  float acc[NE];
#pragma unroll
  for (int e = 0; e < NE; e++) acc[e] = 0.f;
  const float* xrow = x + (size_t)t * HD;
  for (int j = 0; j < HD; j += 64) {
    float xv = xrow[j + lane];
#pragma unroll
    for (int e = 0; e < NE; e++) acc[e] += xv * rws[e * HD + j + lane];
  }
#pragma unroll
  for (int e = 0; e < NE; e++)
    for (int off = 32; off > 0; off >>= 1) acc[e] += __shfl_xor(acc[e], off, 64);
  if (lane == 0) {
#pragma unroll
    for (int e = 0; e < NE; e++) logits_out[t * NE + e] = acc[e];
    int e0 = 0;
#pragma unroll
    for (int e = 1; e < NE; e++) if (acc[e] > acc[e0]) e0 = e;
    int e1 = (e0 == 0) ? 1 : 0;
#pragma unroll
    for (int e = 0; e < NE; e++)
      if (e != e0 && e != e1 && acc[e] > acc[e1]) e1 = e;
    float b = __expf(acc[e1] - acc[e0]);
    float g0 = 1.f / (1.f + b);
    float g1 = 1.f - g0;
    int p0 = atomicAdd(&counts[e0], 1);
    pair_rowid[e0 * T + p0] = t * 2;
    pair_gate[e0 * T + p0] = g0;
    int p1 = atomicAdd(&counts[e1], 1);
    pair_rowid[e1 * T + p1] = t * 2 + 1;
    pair_gate[e1 * T + p1] = g1;
  }
}

// ---------- GEMM1: h = gelu(x@w1_e^T) * (x@v_e^T) -> hb bf16 ----------
// 128x128 tile, BK=64, glds staging with 16B-granule XOR swizzle
__global__ __launch_bounds__(256) void gemm1_kernel(
    const unsigned short* __restrict__ xb, const unsigned short* __restrict__ w1b,
    const unsigned short* __restrict__ vb, unsigned short* __restrict__ hb,
    const int* __restrict__ pair_rowid, const int* __restrict__ counts) {
  int e = blockIdx.z;
  int cnt = counts[e];
  int row0 = blockIdx.y * 128;
  if (row0 >= cnt) return;
  __shared__ unsigned short As[128 * 64];
  __shared__ unsigned short B1s[128 * 64];
  __shared__ unsigned short B2s[128 * 64];
  __shared__ int rids[128];
  int tid = threadIdx.x;
  if (tid < 128) {
    int idx = row0 + tid; if (idx > cnt - 1) idx = cnt - 1;
    rids[tid] = pair_rowid[e * T + idx];
  }
  __syncthreads();
  int lane = tid & 63, wid = tid >> 6;
  int wr = wid >> 1, wc = wid & 1;
  int col0 = blockIdx.x * 128;
  // staging: chunk cid=c*4+wid covers rows cid*8..cid*8+7 (1KB each)
  int gr = lane >> 3, gc = lane & 7;
  const unsigned short *aA[4], *aB1[4], *aB2[4];
#pragma unroll
  for (int c = 0; c < 4; c++) {
    int row = (c * 4 + wid) * 8 + gr;
    int tok = rids[row] >> 1;
    int kswz = ((gc ^ (row & 7)) * 8);
    aA[c]  = xb  + (size_t)tok * HD + kswz;
    aB1[c] = w1b + ((size_t)(e * ID + col0 + row)) * HD + kswz;
    aB2[c] = vb  + ((size_t)(e * ID + col0 + row)) * HD + kswz;
  }
  f32x4 acc1[4][4] = {};
  f32x4 acc3[4][4] = {};
  int mrow = lane & 15, kq = lane >> 4;  // kq = base granule 0..3
  int swzm = mrow & 7;
  for (int kt = 0; kt < HD; kt += 64) {
#pragma unroll
    for (int c = 0; c < 4; c++) {
      int lo = (c * 4 + wid) * 512;
      glds16(aA[c] + kt, &As[lo]);
      glds16(aB1[c] + kt, &B1s[lo]);
      glds16(aB2[c] + kt, &B2s[lo]);
    }
    __syncthreads();
#pragma unroll
    for (int kk = 0; kk < 2; kk++) {
      int g = kk * 4 + kq;
      bf16x8 a[4], b1[4], b2[4];
#pragma unroll
      for (int mi = 0; mi < 4; mi++) {
        int row = wr * 64 + mi * 16 + mrow;
        a[mi] = *(const bf16x8*)&As[row * 64 + ((g ^ swzm) * 8)];
      }
#pragma unroll
      for (int ni = 0; ni < 4; ni++) {
        int row = wc * 64 + ni * 16 + mrow;
        b1[ni] = *(const bf16x8*)&B1s[row * 64 + ((g ^ swzm) * 8)];
        b2[ni] = *(const bf16x8*)&B2s[row * 64 + ((g ^ swzm) * 8)];
      }
#pragma unroll
      for (int mi = 0; mi < 4; mi++)
#pragma unroll
        for (int ni = 0; ni < 4; ni++) {
          acc1[mi][ni] = __builtin_amdgcn_mfma_f32_16x16x32_bf16(a[mi], b1[ni], acc1[mi][ni], 0, 0, 0);
          acc3[mi][ni] = __builtin_amdgcn_mfma_f32_16x16x32_bf16(a[mi], b2[ni], acc3[mi][ni], 0, 0, 0);
        }
    }
    __syncthreads();
  }
  int dcol = lane & 15, drow4 = (lane >> 4) * 4;
#pragma unroll
  for (int mi = 0; mi < 4; mi++)
#pragma unroll
    for (int ni = 0; ni < 4; ni++)
#pragma unroll
      for (int r = 0; r < 4; r++) {
        int lr = wr * 64 + mi * 16 + drow4 + r;
        if (row0 + lr < cnt) {
          float g1v = acc1[mi][ni][r];
          float g3v = acc3[mi][ni][r];
          float hval = 0.5f * g1v * (1.f + erff(g1v * 0.70710678118654752f)) * g3v;
          int rowid = rids[lr];
          hb[(size_t)rowid * ID + col0 + wc * 64 + ni * 16 + dcol] = f2bf(hval);
        }
      }
}

// ---------- GEMM2: y = h @ w2_e^T, gate, atomic-add ----------
__global__ __launch_bounds__(256) void gemm2_kernel(
    const unsigned short* __restrict__ hb, const unsigned short* __restrict__ w2b,
    float* __restrict__ out, const int* __restrict__ pair_rowid,
    const float* __restrict__ pair_gate, const int* __restrict__ counts) {
  int e = blockIdx.z;
  int cnt = counts[e];
  int row0 = blockIdx.y * 128;
  if (row0 >= cnt) return;
  __shared__ unsigned short As[128 * 64];
  __shared__ unsigned short Bs[128 * 64];
  __shared__ int rids[128];
  __shared__ float gts[128];
  int tid = threadIdx.x;
  if (tid < 128) {
    int idx = row0 + tid; if (idx > cnt - 1) idx = cnt - 1;
    rids[tid] = pair_rowid[e * T + idx];
    gts[tid] = pair_gate[e * T + idx];
  }
  __syncthreads();
  int lane = tid & 63, wid = tid >> 6;
  int wr = wid >> 1, wc = wid & 1;
  int col0 = blockIdx.x * 128;
  int gr = lane >> 3, gc = lane & 7;
  const unsigned short *aA[4], *aB[4];
#pragma unroll
  for (int c = 0; c < 4; c++) {
    int row = (c * 4 + wid) * 8 + gr;
    int kswz = ((gc ^ (row & 7)) * 8);
    aA[c] = hb  + (size_t)rids[row] * ID + kswz;
    aB[c] = w2b + ((size_t)(e * HD + col0 + row)) * ID + kswz;
  }
  f32x4 acc[4][4] = {};
  int mrow = lane & 15, kq = lane >> 4;
  int swzm = mrow & 7;
  for (int kt = 0; kt < ID; kt += 64) {
#pragma unroll
    for (int c = 0; c < 4; c++) {
      int lo = (c * 4 + wid) * 512;
      glds16(aA[c] + kt, &As[lo]);
      glds16(aB[c] + kt, &Bs[lo]);
    }
    __syncthreads();
#pragma unroll
    for (int kk = 0; kk < 2; kk++) {
      int g = kk * 4 + kq;
      bf16x8 a[4], b[4];
#pragma unroll
      for (int mi = 0; mi < 4; mi++) {
        int row = wr * 64 + mi * 16 + mrow;
        a[mi] = *(const bf16x8*)&As[row * 64 + ((g ^ swzm) * 8)];
      }
#pragma unroll
      for (int ni = 0; ni < 4; ni++) {
        int row = wc * 64 + ni * 16 + mrow;
        b[ni] = *(const bf16x8*)&Bs[row * 64 + ((g ^ swzm) * 8)];
      }
#pragma unroll
      for (int mi = 0; mi < 4; mi++)
#pragma unroll
        for (int ni = 0; ni < 4; ni++)
          acc[mi][ni] = __builtin_amdgcn_mfma_f32_16x16x32_bf16(a[mi], b[ni], acc[mi][ni], 0, 0, 0);
    }
    __syncthreads();
  }
  int dcol = lane & 15, drow4 = (lane >> 4) * 4;
#pragma unroll
  for (int mi = 0; mi < 4; mi++)
#pragma unroll
    for (int ni = 0; ni < 4; ni++)
#pragma unroll
      for (int r = 0; r < 4; r++) {
        int lr = wr * 64 + mi * 16 + drow4 + r;
        if (row0 + lr < cnt) {
          int tokrow = rids[lr] >> 1;
          float val = gts[lr] * acc[mi][ni][r];
          atomicAdd(&out[(size_t)tokrow * HD + col0 + wc * 64 + ni * 16 + dcol], val);
        }
      }
}

extern "C" void kernel_launch(void* const* d_in, const int* in_sizes, int n_in,
                              void* d_out, int out_size, void* d_ws, size_t ws_size,
                              hipStream_t stream) {
  const float* x  = (const float*)d_in[0];
  const float* rw = (const float*)d_in[1];
  const float* w1 = (const float*)d_in[2];
  const float* v  = (const float*)d_in[3];
  const float* w2 = (const float*)d_in[4];
  float* out = (float*)d_out;
  float* logits_out = out + (size_t)T * HD;

  char* ws = (char*)d_ws;
  unsigned short* xb  = (unsigned short*)(ws);                      // 4 MB
  unsigned short* hb  = (unsigned short*)(ws + (4u << 20));         // 16 MB
  unsigned short* w1b = (unsigned short*)(ws + (20u << 20));        // 32 MB
  unsigned short* vb  = (unsigned short*)(ws + (52u << 20));        // 32 MB
  unsigned short* w2b = (unsigned short*)(ws + (84u << 20));        // 32 MB
  int*   pair_rowid   = (int*)  (ws + (116u << 20));                // 64 KB
  float* pair_gate    = (float*)(ws + (116u << 20) + 65536);        // 64 KB
  int*   counts       = (int*)  (ws + (116u << 20) + 131072);       // 32 B

  hipMemsetAsync(out, 0, (size_t)T * HD * sizeof(float), stream);
  hipMemsetAsync(counts, 0, NE * sizeof(int), stream);

  // weights: 3 tensors x 16.78M elems, 8 elems/thread
  cast_w_kernel<<<dim3(8192, 3), 256, 0, stream>>>(w1, v, w2, w1b, vb, w2b);
  cast_x_kernel<<<(T * HD) / (256 * 8), 256, 0, stream>>>(x, xb);
  router_kernel<<<T / 4, 256, 0, stream>>>(x, rw, logits_out, pair_rowid,
                                           pair_gate, counts);
  gemm1_kernel<<<dim3(ID / 128, T / 128, NE), 256, 0, stream>>>(
      xb, w1b, vb, hb, pair_rowid, counts);
  gemm2_kernel<<<dim3(HD / 128, T / 128, NE), 256, 0, stream>>>(
      hb, w2b, out, pair_rowid, pair_gate, counts);
}